// Round 5
// baseline (248.566 us; speedup 1.0000x reference)
//
#include <hip/hip_runtime.h>

#define BLOCK 256
#define GRID 2048
#define UNROLL 8

typedef float f32x4 __attribute__((ext_vector_type(4)));
typedef int   i32x2 __attribute__((ext_vector_type(2)));

// Real kernel: same block-contiguous stride-1 layout as round 4, but loads are
// NONTEMPORAL (bypass cache allocation) and unroll is 8. Math unchanged.
__global__ __launch_bounds__(BLOCK) void loss_partial_kernel(
    const f32x4* __restrict__ pred4,  // N/2 elements (2 rows per float4)
    const i32x2* __restrict__ tgt2,   // N/2 elements (2 targets per int2)
    float* __restrict__ partials,     // GRID
    int npairs)                       // N/2
{
    const int ppb  = (npairs + GRID - 1) / GRID;   // 4096 pairs per block
    const int base = blockIdx.x * ppb;
    const int end  = min(base + ppb, npairs);

    float acc = 0.0f;
    int k = base + threadIdx.x;

    for (; k + (UNROLL - 1) * BLOCK < end; k += UNROLL * BLOCK) {
        f32x4 p[UNROLL];
        i32x2 t[UNROLL];
#pragma unroll
        for (int u = 0; u < UNROLL; ++u) p[u] = __builtin_nontemporal_load(&pred4[k + u * BLOCK]);
#pragma unroll
        for (int u = 0; u < UNROLL; ++u) t[u] = __builtin_nontemporal_load(&tgt2[k + u * BLOCK]);
#pragma unroll
        for (int u = 0; u < UNROLL; ++u) {
            {
                bool z = (t[u][0] == 0);
                float a = z ? p[u][0] : p[u][1];
                float b = z ? p[u][1] : p[u][0];
                float d = 1.0f - a;
                acc += fmaf(d, d, b * b) + ((a < b) ? 2.0f : 0.0f);
            }
            {
                bool z = (t[u][1] == 0);
                float a = z ? p[u][2] : p[u][3];
                float b = z ? p[u][3] : p[u][2];
                float d = 1.0f - a;
                acc += fmaf(d, d, b * b) + ((a < b) ? 2.0f : 0.0f);
            }
        }
    }
    for (; k < end; k += BLOCK) {   // tail (not taken at N=16777216)
        f32x4 p = __builtin_nontemporal_load(&pred4[k]);
        i32x2 t = __builtin_nontemporal_load(&tgt2[k]);
        {
            bool z = (t[0] == 0);
            float a = z ? p[0] : p[1];
            float b = z ? p[1] : p[0];
            float d = 1.0f - a;
            acc += fmaf(d, d, b * b) + ((a < b) ? 2.0f : 0.0f);
        }
        {
            bool z = (t[1] == 0);
            float a = z ? p[2] : p[3];
            float b = z ? p[3] : p[2];
            float d = 1.0f - a;
            acc += fmaf(d, d, b * b) + ((a < b) ? 2.0f : 0.0f);
        }
    }

#pragma unroll
    for (int off = 32; off > 0; off >>= 1)
        acc += __shfl_down(acc, off, 64);

    __shared__ float wsum[BLOCK / 64];
    const int lane = threadIdx.x & 63;
    const int wid  = threadIdx.x >> 6;
    if (lane == 0) wsum[wid] = acc;
    __syncthreads();
    if (threadIdx.x == 0) {
        float s = 0.0f;
#pragma unroll
        for (int w = 0; w < BLOCK / 64; ++w) s += wsum[w];
        partials[blockIdx.x] = s;
    }
}

__global__ __launch_bounds__(BLOCK) void loss_final_kernel(
    const float* __restrict__ partials, float* __restrict__ out,
    int nparts, float inv_n)
{
    float acc = 0.0f;
    for (int i = threadIdx.x; i < nparts; i += BLOCK)
        acc += partials[i];
#pragma unroll
    for (int off = 32; off > 0; off >>= 1)
        acc += __shfl_down(acc, off, 64);

    __shared__ float wsum[BLOCK / 64];
    const int lane = threadIdx.x & 63;
    const int wid  = threadIdx.x >> 6;
    if (lane == 0) wsum[wid] = acc;
    __syncthreads();
    if (threadIdx.x == 0) {
        float s = 0.0f;
#pragma unroll
        for (int w = 0; w < BLOCK / 64; ++w) s += wsum[w];
        out[0] = s * inv_n;
    }
}

// DIAGNOSTIC PROBE: pure contiguous read-sum of pred (128 MB), PLAIN loads,
// no int loads, no branches. Measures the achievable read BW ceiling in this
// harness context. Launched last; writes into a private d_ws region.
__global__ __launch_bounds__(BLOCK) void probe_read_kernel(
    const f32x4* __restrict__ src, float* __restrict__ sink, int nvec)
{
    const int vpb  = (nvec + GRID - 1) / GRID;     // 4096 vec4 per block
    const int base = blockIdx.x * vpb;
    const int end  = min(base + vpb, nvec);

    float acc = 0.0f;
    int k = base + threadIdx.x;
    for (; k + (UNROLL - 1) * BLOCK < end; k += UNROLL * BLOCK) {
        f32x4 v[UNROLL];
#pragma unroll
        for (int u = 0; u < UNROLL; ++u) v[u] = src[k + u * BLOCK];
#pragma unroll
        for (int u = 0; u < UNROLL; ++u)
            acc += (v[u][0] + v[u][1]) + (v[u][2] + v[u][3]);
    }
    for (; k < end; k += BLOCK) {
        f32x4 v = src[k];
        acc += (v[0] + v[1]) + (v[2] + v[3]);
    }

#pragma unroll
    for (int off = 32; off > 0; off >>= 1)
        acc += __shfl_down(acc, off, 64);
    if ((threadIdx.x & 63) == 0)
        sink[blockIdx.x * 4 + (threadIdx.x >> 6)] = acc;
}

extern "C" void kernel_launch(void* const* d_in, const int* in_sizes, int n_in,
                              void* d_out, int out_size, void* d_ws, size_t ws_size,
                              hipStream_t stream) {
    const float* pred = (const float*)d_in[0];
    const int* target = (const int*)d_in[1];
    float* out = (float*)d_out;
    float* ws_f = (float*)d_ws;

    int n = in_sizes[1];
    if (n * 2 != in_sizes[0]) n = in_sizes[0] / 2;   // defensive fallback
    const int npairs = n / 2;

    loss_partial_kernel<<<GRID, BLOCK, 0, stream>>>(
        (const f32x4*)pred, (const i32x2*)target, ws_f, npairs);
    loss_final_kernel<<<1, BLOCK, 0, stream>>>(ws_f, out, GRID, 1.0f / (float)n);

    // Diagnostic probe AFTER the real kernels; private ws region at offset 64K floats.
    probe_read_kernel<<<GRID, BLOCK, 0, stream>>>(
        (const f32x4*)pred, ws_f + 65536, npairs);
}

// Round 6
// 214.893 us; speedup vs baseline: 1.1567x; 1.1567x over previous
//
#include <hip/hip_runtime.h>

#define BLOCK 256
#define GRID 2048
#define UNROLL 8

typedef float f32x4 __attribute__((ext_vector_type(4)));
typedef int   i32x2 __attribute__((ext_vector_type(2)));

// Block-contiguous stride-1 layout, nontemporal loads, unroll x8.
// One float4 = probs of 2 consecutive rows; one int2 = their targets.
__global__ __launch_bounds__(BLOCK) void loss_partial_kernel(
    const f32x4* __restrict__ pred4,  // N/2 elements (2 rows per float4)
    const i32x2* __restrict__ tgt2,   // N/2 elements (2 targets per int2)
    float* __restrict__ partials,     // GRID
    int npairs)                       // N/2
{
    const int ppb  = (npairs + GRID - 1) / GRID;   // 4096 pairs per block
    const int base = blockIdx.x * ppb;
    const int end  = min(base + ppb, npairs);

    float acc = 0.0f;
    int k = base + threadIdx.x;

    for (; k + (UNROLL - 1) * BLOCK < end; k += UNROLL * BLOCK) {
        f32x4 p[UNROLL];
        i32x2 t[UNROLL];
#pragma unroll
        for (int u = 0; u < UNROLL; ++u) p[u] = __builtin_nontemporal_load(&pred4[k + u * BLOCK]);
#pragma unroll
        for (int u = 0; u < UNROLL; ++u) t[u] = __builtin_nontemporal_load(&tgt2[k + u * BLOCK]);
#pragma unroll
        for (int u = 0; u < UNROLL; ++u) {
            {
                bool z = (t[u][0] == 0);
                float a = z ? p[u][0] : p[u][1];
                float b = z ? p[u][1] : p[u][0];
                float d = 1.0f - a;
                acc += fmaf(d, d, b * b) + ((a < b) ? 2.0f : 0.0f);
            }
            {
                bool z = (t[u][1] == 0);
                float a = z ? p[u][2] : p[u][3];
                float b = z ? p[u][3] : p[u][2];
                float d = 1.0f - a;
                acc += fmaf(d, d, b * b) + ((a < b) ? 2.0f : 0.0f);
            }
        }
    }
    for (; k < end; k += BLOCK) {   // tail (not taken at N=16777216)
        f32x4 p = __builtin_nontemporal_load(&pred4[k]);
        i32x2 t = __builtin_nontemporal_load(&tgt2[k]);
        {
            bool z = (t[0] == 0);
            float a = z ? p[0] : p[1];
            float b = z ? p[1] : p[0];
            float d = 1.0f - a;
            acc += fmaf(d, d, b * b) + ((a < b) ? 2.0f : 0.0f);
        }
        {
            bool z = (t[1] == 0);
            float a = z ? p[2] : p[3];
            float b = z ? p[3] : p[2];
            float d = 1.0f - a;
            acc += fmaf(d, d, b * b) + ((a < b) ? 2.0f : 0.0f);
        }
    }

#pragma unroll
    for (int off = 32; off > 0; off >>= 1)
        acc += __shfl_down(acc, off, 64);

    __shared__ float wsum[BLOCK / 64];
    const int lane = threadIdx.x & 63;
    const int wid  = threadIdx.x >> 6;
    if (lane == 0) wsum[wid] = acc;
    __syncthreads();
    if (threadIdx.x == 0) {
        float s = 0.0f;
#pragma unroll
        for (int w = 0; w < BLOCK / 64; ++w) s += wsum[w];
        partials[blockIdx.x] = s;
    }
}

__global__ __launch_bounds__(BLOCK) void loss_final_kernel(
    const float* __restrict__ partials, float* __restrict__ out,
    int nparts, float inv_n)
{
    float acc = 0.0f;
    for (int i = threadIdx.x; i < nparts; i += BLOCK)
        acc += partials[i];
#pragma unroll
    for (int off = 32; off > 0; off >>= 1)
        acc += __shfl_down(acc, off, 64);

    __shared__ float wsum[BLOCK / 64];
    const int lane = threadIdx.x & 63;
    const int wid  = threadIdx.x >> 6;
    if (lane == 0) wsum[wid] = acc;
    __syncthreads();
    if (threadIdx.x == 0) {
        float s = 0.0f;
#pragma unroll
        for (int w = 0; w < BLOCK / 64; ++w) s += wsum[w];
        out[0] = s * inv_n;
    }
}

extern "C" void kernel_launch(void* const* d_in, const int* in_sizes, int n_in,
                              void* d_out, int out_size, void* d_ws, size_t ws_size,
                              hipStream_t stream) {
    const float* pred = (const float*)d_in[0];
    const int* target = (const int*)d_in[1];
    float* out = (float*)d_out;
    float* ws_f = (float*)d_ws;

    int n = in_sizes[1];
    if (n * 2 != in_sizes[0]) n = in_sizes[0] / 2;   // defensive fallback
    const int npairs = n / 2;

    loss_partial_kernel<<<GRID, BLOCK, 0, stream>>>(
        (const f32x4*)pred, (const i32x2*)target, ws_f, npairs);
    loss_final_kernel<<<1, BLOCK, 0, stream>>>(ws_f, out, GRID, 1.0f / (float)n);
}